// Round 15
// baseline (316.507 us; speedup 1.0000x reference)
//
#include <hip/hip_runtime.h>
#include <hip/hip_bf16.h>
#include <math.h>

#define N_NODES 20000
#define N_EDGES 320000
#define MAXDEG 64              // P(Poisson(16) >= 64) ~ 2e-18/node; clamped anyway

typedef _Float16 f16x8 __attribute__((ext_vector_type(8)));
typedef _Float16 h2 __attribute__((ext_vector_type(2)));
typedef float f32x4 __attribute__((ext_vector_type(4)));

__device__ __forceinline__ unsigned short f2h_bits(float f) {
    _Float16 h = (_Float16)f;            // RNE f32->f16
    return __builtin_bit_cast(unsigned short, h);
}

// async global->LDS DMA, 16B per lane; LDS dest = wave-uniform base + lane*16
typedef const unsigned int __attribute__((address_space(1)))* gas_ptr;
typedef unsigned int __attribute__((address_space(3)))* las_ptr;
__device__ __forceinline__ void gld16(const unsigned short* g, unsigned short* l) {
    __builtin_amdgcn_global_load_lds((gas_ptr)(const void*)g, (las_ptr)(void*)l, 16, 0, 0);
}

// ---------------------------------------------------------------------------
// setup (R23 form): cnt zeroed via hipMemsetAsync; padded-CSR scatter rides
// as TAIL BLOCKS of prep. One setup launch + memset.
// ---------------------------------------------------------------------------
struct PrepJobs {
    const float* W[9];
    unsigned short* Wt[9];
    int K[9];
    int D[9];
    int tbeg[10];              // 32x32 tile prefix per transpose job
    const float* x;            // fp32 input
    unsigned short* xh;        // f16 output
    int nconv4;                // n/4 float4 groups
    int nconvb;                // conv blocks
    const int* src;            // scatter tail
    const int* dst;
    int* cnt;
    int* csr_pad;
};
__global__ __launch_bounds__(256) void prep_kernel(PrepJobs jb) {
    int bid = blockIdx.x;
    int ntile = jb.tbeg[9];
    if (bid < ntile) {
        __shared__ float ld[32][33];
        int job = 0;
        while (bid >= jb.tbeg[job + 1]) ++job;
        int tl = bid - jb.tbeg[job];
        int K = jb.K[job], D = jb.D[job];
        int TK = K >> 5;
        int td = tl / TK, tk = tl - td * TK;
        int k0 = tk << 5, d0 = td << 5;
        int t = threadIdx.x;
        int c = t & 31, r0 = (t >> 5) << 2;
        const float* Wp = jb.W[job];
#pragma unroll
        for (int jj = 0; jj < 4; ++jj)
            ld[r0 + jj][c] = Wp[(size_t)(k0 + r0 + jj) * D + d0 + c];   // coalesced
        __syncthreads();
        unsigned short* Wtp = jb.Wt[job];
#pragma unroll
        for (int jj = 0; jj < 4; ++jj) {
            int dr = r0 + jj;
            Wtp[(size_t)(d0 + dr) * K + k0 + c] = f2h_bits(ld[c][dr]);  // coalesced
        }
    } else if (bid < ntile + jb.nconvb) {
        int cidx = (bid - ntile) * 256 + (int)threadIdx.x;
        if (cidx < jb.nconv4) {
            int base = cidx * 4;
            float4 v = *(const float4*)(jb.x + base);
            uint2 pk;
            pk.x = (unsigned int)f2h_bits(v.x) | ((unsigned int)f2h_bits(v.y) << 16);
            pk.y = (unsigned int)f2h_bits(v.z) | ((unsigned int)f2h_bits(v.w) << 16);
            *(uint2*)(jb.xh + base) = pk;
        }
    } else {
        int i = (bid - ntile - jb.nconvb) * 256 + (int)threadIdx.x;
        if (i < N_EDGES) {
            int d = jb.dst[i];
            int pos = atomicAdd(&jb.cnt[d], 1);
            if (pos < MAXDEG) jb.csr_pad[(d << 6) + pos] = jb.src[i];
        }
    }
}

// ---------------------------------------------------------------------------
// fused 3-in-1 f16 MFMA GEMM.
// R21: T2 swizzle (conflicts 5.79M->~0). R22: counted-vmcnt dbuf (+3us).
// R24: BK 64->32 with the SAME dbuf pipeline: LDS 64KB -> 32KB -> 4-5
// blocks/CU (was 2). R20 PMC showed latency-bound (MfmaUtil 10%, occ 17%,
// nothing saturated); R22 proved pipeline > syncthreads even at 2 blocks/CU;
// R24 stacks cross-block TLP on top. vmcnt ledger: 4 DMAs/thread/tile;
// steady state 4 old + 4 new -> vmcnt(4) drains exactly the old tile; last
// iter vmcnt(0). Swizzle for 64B row stride: q ^ ((row>>1)&3) on both the
// stage source and the fragment read (involution; rows 0-3 per parity
// cover all 4 bank-quartets -> <=2-way = free). K-order identical -> bit-exact.
// ---------------------------------------------------------------------------
template <int SEED_F32>
__global__ __launch_bounds__(256) void gemm3_kernel(
        const unsigned short* __restrict__ A,    // [M][K] f16
        const unsigned short* __restrict__ Bt,   // [3D][K] f16 (Wl^T|Wr^T|Ws^T)
        unsigned short* __restrict__ xlh,        // [M][D] f16
        unsigned short* __restrict__ xrh,        // [M][D] f16
        unsigned short* __restrict__ seedh,      // [M][D] f16 (SEED_F32==0)
        float* __restrict__ seedf,               // [M][D] fp32 (SEED_F32==1)
        const float* __restrict__ b1,
        const float* __restrict__ b2,
        int M, int K, int D) {
    __shared__ __align__(16) unsigned short Asl[2][128 * 32];
    __shared__ __align__(16) unsigned short Bsl[2][128 * 32];

    int NC = (3 * D) >> 7;               // column tiles
    int MT = (M + 127) >> 7;             // M tiles
    int g = blockIdx.x;
    int xcd = g & 7, slot = g >> 3;
    int m_local = slot / NC, c = slot - m_local * NC;
    int mt = m_local * 8 + xcd;
    if (mt >= MT) return;                // block-uniform -> safe before barriers

    int tid = threadIdx.x;
    int wave = tid >> 6, lane = tid & 63;
    int q = lane >> 4, t = lane & 15;
    int wm = (wave & 1) * 64, wn = (wave >> 1) * 64;
    int bm = mt << 7;
    int bn_all = c << 7;
    int seg = bn_all / D;                // D multiple of 128 -> block-uniform
    int bn = bn_all - seg * D;

    f32x4 acc[4][4];
#pragma unroll
    for (int i = 0; i < 4; ++i)
#pragma unroll
        for (int j = 0; j < 4; ++j) acc[i][j] = (f32x4){0.f, 0.f, 0.f, 0.f};

    int niter = K >> 5;

    // prologue: stage k-tile 0 into buffer 0 (4 DMAs/thread)
    {
#pragma unroll
        for (int rnd = 0; rnd < 2; ++rnd) {
            int ch = rnd * 256 + tid;
            int row = ch >> 2, part = ch & 3;
            int sw = part ^ ((row >> 1) & 3);             // T2 pre-swizzle
            int gr = bm + row; if (gr >= M) gr = M - 1;
            gld16(A + (size_t)gr * K + sw * 8,
                  &Asl[0][(rnd * 256 + wave * 64) * 8]);
        }
#pragma unroll
        for (int rnd = 0; rnd < 2; ++rnd) {
            int ch = rnd * 256 + tid;
            int row = ch >> 2, part = ch & 3;
            int sw = part ^ ((row >> 1) & 3);
            gld16(Bt + (size_t)(bn_all + row) * K + sw * 8,
                  &Bsl[0][(rnd * 256 + wave * 64) * 8]);
        }
    }

    for (int i = 0; i < niter; ++i) {
        int cur = i & 1;
        if (i + 1 < niter) {
            int k0 = (i + 1) << 5;
            int nb = cur ^ 1;
#pragma unroll
            for (int rnd = 0; rnd < 2; ++rnd) {
                int ch = rnd * 256 + tid;
                int row = ch >> 2, part = ch & 3;
                int sw = part ^ ((row >> 1) & 3);
                int gr = bm + row; if (gr >= M) gr = M - 1;
                gld16(A + (size_t)gr * K + k0 + sw * 8,
                      &Asl[nb][(rnd * 256 + wave * 64) * 8]);
            }
#pragma unroll
            for (int rnd = 0; rnd < 2; ++rnd) {
                int ch = rnd * 256 + tid;
                int row = ch >> 2, part = ch & 3;
                int sw = part ^ ((row >> 1) & 3);
                gld16(Bt + (size_t)(bn_all + row) * K + k0 + sw * 8,
                      &Bsl[nb][(rnd * 256 + wave * 64) * 8]);
            }
            asm volatile("s_waitcnt vmcnt(4)" ::: "memory");   // drain iter i only
        } else {
            asm volatile("s_waitcnt vmcnt(0)" ::: "memory");   // final iter: drain all
        }
        __builtin_amdgcn_s_barrier();            // all waves' iter-i DMAs done
        __builtin_amdgcn_sched_barrier(0);       // pin: no LDS-read hoist above

        {
            f16x8 an[4], am[4];
#pragma unroll
            for (int jn = 0; jn < 4; ++jn) {
                int rb = wn + jn * 16 + t;
                an[jn] = *(const f16x8*)(&Bsl[cur][rb * 32 + ((q ^ ((rb >> 1) & 3)) << 3)]);
            }
#pragma unroll
            for (int im = 0; im < 4; ++im) {
                int ra = wm + im * 16 + t;
                am[im] = *(const f16x8*)(&Asl[cur][ra * 32 + ((q ^ ((ra >> 1) & 3)) << 3)]);
            }
#pragma unroll
            for (int jn = 0; jn < 4; ++jn)
#pragma unroll
                for (int im = 0; im < 4; ++im)
                    acc[jn][im] = __builtin_amdgcn_mfma_f32_16x16x32_f16(an[jn], am[im], acc[jn][im], 0, 0, 0);
        }
        __builtin_amdgcn_s_barrier();            // protect buf[cur] before reuse
        __builtin_amdgcn_sched_barrier(0);       // pin: no next-stage DMA hoist above
    }

#pragma unroll
    for (int jn = 0; jn < 4; ++jn) {
        int n0 = bn + wn + jn * 16 + q * 4;
        float bx = 0.f, by = 0.f, bz = 0.f, bw = 0.f;
        if (seg == 2) {
            float4 bb1 = *(const float4*)(b1 + n0);
            float4 bb2 = *(const float4*)(b2 + n0);
            bx = bb1.x + bb2.x; by = bb1.y + bb2.y;
            bz = bb1.z + bb2.z; bw = bb1.w + bb2.w;
        }
#pragma unroll
        for (int im = 0; im < 4; ++im) {
            int m = bm + wm + im * 16 + t;
            if (m < M) {
                float v0 = acc[jn][im][0] + bx;
                float v1 = acc[jn][im][1] + by;
                float v2 = acc[jn][im][2] + bz;
                float v3 = acc[jn][im][3] + bw;
                size_t idx = (size_t)m * D + n0;
                if (seg == 2 && SEED_F32) {
                    *(float4*)(seedf + idx) = make_float4(v0, v1, v2, v3);
                } else {
                    uint2 pk;
                    pk.x = (unsigned int)f2h_bits(v0) | ((unsigned int)f2h_bits(v1) << 16);
                    pk.y = (unsigned int)f2h_bits(v2) | ((unsigned int)f2h_bits(v3) << 16);
                    unsigned short* dstp = (seg == 0) ? xlh : (seg == 1) ? xrh : seedh;
                    *(uint2*)(dstp + idx) = pk;
                }
            }
        }
    }
}

// ---------------------------------------------------------------------------
// fused per-node agg (R22 exact 128-thread form — best measured ~53.0us;
// closed after 6 structural variants incl. R23's clean 512-thread occupancy
// probe: occ pinned at 40% regardless -> random-gather miss-path floor).
// ---------------------------------------------------------------------------
template <int D, int SEED_H, int WRITE_H, int RELU>
__global__ __launch_bounds__(128) void fused_agg_kernel(
        const unsigned short* __restrict__ xl,
        const unsigned short* __restrict__ xr,
        const float* __restrict__ att,
        const int* __restrict__ cnt,
        const int* __restrict__ csr_pad,
        const unsigned short* __restrict__ seedh,
        const float* __restrict__ seedf,
        float* __restrict__ outf,
        unsigned short* __restrict__ outh) {
    constexpr int VPL = D / 64;
    constexpr int HP = VPL / 2;
    typedef _Float16 hvec __attribute__((ext_vector_type(VPL)));

    int wave = threadIdx.x >> 6, lane = threadIdx.x & 63;
    int n = blockIdx.x * 2 + wave;
    if (n >= N_NODES) return;
    int cn = cnt[n]; if (cn > MAXDEG) cn = MAXDEG;
    int beg = n << 6;
    int end = beg + cn;

    h2 xr_h[HP], att_h[HP];
    hvec xrv = *(const hvec*)(xr + (size_t)n * D + lane * VPL);
#pragma unroll
    for (int pp = 0; pp < HP; ++pp) {
        xr_h[pp] = (h2){xrv[2 * pp], xrv[2 * pp + 1]};
        att_h[pp] = (h2){(_Float16)att[lane * VPL + 2 * pp],
                         (_Float16)att[lane * VPL + 2 * pp + 1]};
    }

    float acc[VPL];
#pragma unroll
    for (int v = 0; v < VPL; ++v) acc[v] = 0.f;
    float m = -INFINITY, s = 0.f;

    const _Float16 c02 = (_Float16)0.2f;
    int lb0 = lane & 1;
    int lb1 = lane & 2;

    int nfull = cn >> 2;
    int j = beg;
    int i0 = 0, i1 = 0, i2 = 0, i3 = 0;
    if (nfull > 0) {
        i0 = csr_pad[beg]; i1 = csr_pad[beg + 1];
        i2 = csr_pad[beg + 2]; i3 = csr_pad[beg + 3];
    }
    for (int b = 0; b < nfull; ++b) {
        int s0 = i0, s1 = i1, s2 = i2, s3 = i3;
        int jn4 = j + 4;
        if (b + 1 < nfull) {            // prefetch next batch's indices
            i0 = csr_pad[jn4]; i1 = csr_pad[jn4 + 1];
            i2 = csr_pad[jn4 + 2]; i3 = csr_pad[jn4 + 3];
        }
        hvec x0 = *(const hvec*)(xl + (size_t)s0 * D + lane * VPL);
        hvec x1 = *(const hvec*)(xl + (size_t)s1 * D + lane * VPL);
        hvec x2 = *(const hvec*)(xl + (size_t)s2 * D + lane * VPL);
        hvec x3 = *(const hvec*)(xl + (size_t)s3 * D + lane * VPL);
        float p0 = 0.f, p1 = 0.f, p2 = 0.f, p3 = 0.f;
#pragma unroll
        for (int pp = 0; pp < HP; ++pp) {
            h2 a0 = (h2){x0[2 * pp], x0[2 * pp + 1]};
            h2 a1 = (h2){x1[2 * pp], x1[2 * pp + 1]};
            h2 a2 = (h2){x2[2 * pp], x2[2 * pp + 1]};
            h2 a3 = (h2){x3[2 * pp], x3[2 * pp + 1]};
            h2 z0 = a0 + xr_h[pp];
            h2 z1 = a1 + xr_h[pp];
            h2 z2 = a2 + xr_h[pp];
            h2 z3 = a3 + xr_h[pp];
            h2 l0 = __builtin_elementwise_max(z0, z0 * c02);   // leaky_relu
            h2 l1 = __builtin_elementwise_max(z1, z1 * c02);
            h2 l2 = __builtin_elementwise_max(z2, z2 * c02);
            h2 l3 = __builtin_elementwise_max(z3, z3 * c02);
#if __has_builtin(__builtin_amdgcn_fdot2)
            p0 = __builtin_amdgcn_fdot2(l0, att_h[pp], p0, false);
            p1 = __builtin_amdgcn_fdot2(l1, att_h[pp], p1, false);
            p2 = __builtin_amdgcn_fdot2(l2, att_h[pp], p2, false);
            p3 = __builtin_amdgcn_fdot2(l3, att_h[pp], p3, false);
#else
            p0 += (float)l0.x * (float)att_h[pp].x + (float)l0.y * (float)att_h[pp].y;
            p1 += (float)l1.x * (float)att_h[pp].x + (float)l1.y * (float)att_h[pp].y;
            p2 += (float)l2.x * (float)att_h[pp].x + (float)l2.y * (float)att_h[pp].y;
            p3 += (float)l3.x * (float)att_h[pp].x + (float)l3.y * (float)att_h[pp].y;
#endif
        }
        // butterfly tree: stride 1 (4->2 regs), stride 2 (2->1), strides 4..32
        float k0 = lb0 ? p1 : p0, sn0 = lb0 ? p0 : p1;
        float k1 = lb0 ? p3 : p2, sn1 = lb0 ? p2 : p3;
        k0 += __shfl_xor(sn0, 1, 64);
        k1 += __shfl_xor(sn1, 1, 64);
        float k = lb1 ? k1 : k0, sn = lb1 ? k0 : k1;
        k += __shfl_xor(sn, 2, 64);
        k += __shfl_xor(k, 4, 64);
        k += __shfl_xor(k, 8, 64);
        k += __shfl_xor(k, 16, 64);
        k += __shfl_xor(k, 32, 64);
        // lane l holds full score of edge (l&3); broadcast all four
        float q0 = __shfl(k, 0, 64);
        float q1 = __shfl(k, 1, 64);
        float q2 = __shfl(k, 2, 64);
        float q3 = __shfl(k, 3, 64);

        float mn = fmaxf(m, fmaxf(fmaxf(q0, q1), fmaxf(q2, q3)));
        float sc = __expf(m - mn);           // first iter: exp(-inf)=0
        float e0 = __expf(q0 - mn);
        float e1 = __expf(q1 - mn);
        float e2 = __expf(q2 - mn);
        float e3 = __expf(q3 - mn);
        s = s * sc + e0 + e1 + e2 + e3;
#pragma unroll
        for (int v = 0; v < VPL; ++v)
            acc[v] = acc[v] * sc + e0 * (float)x0[v] + e1 * (float)x1[v]
                                 + e2 * (float)x2[v] + e3 * (float)x3[v];
        m = mn;
        j = jn4;
    }
    for (; j < end; ++j) {   // tail (0-3 edges)
        int s0 = csr_pad[j];
        hvec x0 = *(const hvec*)(xl + (size_t)s0 * D + lane * VPL);
        float p0 = 0.f;
#pragma unroll
        for (int pp = 0; pp < HP; ++pp) {
            h2 a0 = (h2){x0[2 * pp], x0[2 * pp + 1]};
            h2 z0 = a0 + xr_h[pp];
            h2 l0 = __builtin_elementwise_max(z0, z0 * c02);
#if __has_builtin(__builtin_amdgcn_fdot2)
            p0 = __builtin_amdgcn_fdot2(l0, att_h[pp], p0, false);
#else
            p0 += (float)l0.x * (float)att_h[pp].x + (float)l0.y * (float)att_h[pp].y;
#endif
        }
#pragma unroll
        for (int o = 32; o > 0; o >>= 1) p0 += __shfl_xor(p0, o, 64);
        float mn = fmaxf(m, p0);
        float sc = __expf(m - mn);
        float e0 = __expf(p0 - mn);
        s = s * sc + e0;
#pragma unroll
        for (int v = 0; v < VPL; ++v) acc[v] = acc[v] * sc + e0 * (float)x0[v];
        m = mn;
    }

    float sinv = 1.0f / (s + 1e-16f);
    size_t base = (size_t)n * D + lane * VPL;
    float sd[VPL];
    if (SEED_H) {
        hvec sv = *(const hvec*)(seedh + base);
#pragma unroll
        for (int v = 0; v < VPL; ++v) sd[v] = (float)sv[v];
    } else {
#pragma unroll
        for (int v = 0; v < VPL; ++v) sd[v] = seedf[base + v];
    }
#pragma unroll
    for (int v = 0; v < VPL; ++v) {
        float val = sd[v] + acc[v] * sinv;
        if (RELU) val = fmaxf(val, 0.f);
        if (WRITE_H) outh[base + v] = f2h_bits(val);
        else         outf[base + v] = val;
    }
}

// ---------------------------------------------------------------------------
// host-side layer driver
// ---------------------------------------------------------------------------
static void run_layer(const unsigned short* hact, int K, int D,
                      const unsigned short* Wcat,
                      const float* att, const float* bc, const float* bs,
                      unsigned short* xlh, unsigned short* xrh,
                      unsigned short* seedh, float* seedf,
                      const int* cnt, const int* csr_pad,
                      float* outf, unsigned short* outh, int final_layer,
                      hipStream_t stream) {
    int NC = 3 * D / 128;
    int MT = (N_NODES + 127) / 128;
    int nblk = 8 * ((MT + 7) / 8) * NC;   // XCD-swizzled 1D grid
    if (final_layer)
        hipLaunchKernelGGL((gemm3_kernel<1>), dim3(nblk), dim3(256), 0, stream, hact, Wcat,
                           xlh, xrh, (unsigned short*)nullptr, seedf, bs, bc, N_NODES, K, D);
    else
        hipLaunchKernelGGL((gemm3_kernel<0>), dim3(nblk), dim3(256), 0, stream, hact, Wcat,
                           xlh, xrh, seedh, (float*)nullptr, bs, bc, N_NODES, K, D);

    dim3 agrid((N_NODES + 1) / 2);
    if (D == 512) {
        hipLaunchKernelGGL((fused_agg_kernel<512, 1, 1, 1>), agrid, dim3(128), 0, stream,
                           xlh, xrh, att, cnt, csr_pad, seedh, (const float*)nullptr,
                           (float*)nullptr, outh);
    } else if (D == 256) {
        hipLaunchKernelGGL((fused_agg_kernel<256, 1, 1, 1>), agrid, dim3(128), 0, stream,
                           xlh, xrh, att, cnt, csr_pad, seedh, (const float*)nullptr,
                           (float*)nullptr, outh);
    } else {
        hipLaunchKernelGGL((fused_agg_kernel<128, 0, 0, 0>), agrid, dim3(128), 0, stream,
                           xlh, xrh, att, cnt, csr_pad, (const unsigned short*)nullptr, seedf,
                           outf, (unsigned short*)nullptr);
    }
}

extern "C" void kernel_launch(void* const* d_in, const int* in_sizes, int n_in,
                              void* d_out, int out_size, void* d_ws, size_t ws_size,
                              hipStream_t stream) {
    const float* x = (const float*)d_in[0];
    const int* ei = (const int*)d_in[1];
    const int* src = ei;
    const int* dst = ei + N_EDGES;

    const float* Wl1 = (const float*)d_in[2];
    const float* Wr1 = (const float*)d_in[3];
    const float* att1 = (const float*)d_in[4];
    const float* bc1 = (const float*)d_in[5];
    const float* Ws1 = (const float*)d_in[6];
    const float* bs1 = (const float*)d_in[7];
    const float* Wl2 = (const float*)d_in[8];
    const float* Wr2 = (const float*)d_in[9];
    const float* att2 = (const float*)d_in[10];
    const float* bc2 = (const float*)d_in[11];
    const float* Ws2 = (const float*)d_in[12];
    const float* bs2 = (const float*)d_in[13];
    const float* Wl3 = (const float*)d_in[14];
    const float* Wr3 = (const float*)d_in[15];
    const float* att3 = (const float*)d_in[16];
    const float* bc3 = (const float*)d_in[17];
    const float* Ws3 = (const float*)d_in[18];
    const float* bs3 = (const float*)d_in[19];

    // workspace carve
    const size_t NF = (size_t)N_NODES * 512;
    const size_t NH = (size_t)N_NODES * 256;
    unsigned short* xlh   = (unsigned short*)d_ws;      // N x 512 f16 (reused per layer)
    unsigned short* xrh   = xlh + NF;
    unsigned short* seedh = xrh + NF;                   // N x 512 f16 (layers 1-2)
    unsigned short* xhf   = seedh + NF;                 // x as f16: N x 256
    unsigned short* h1h   = xhf + NH;                   // layer1 out: N x 512
    unsigned short* h2h   = h1h + NF;                   // layer2 out: N x 256
    unsigned short* Wcat1 = h2h + NH;                   // 3 x 512 x 256
    unsigned short* Wcat2 = Wcat1 + 3 * 512 * 256;      // 3 x 256 x 512
    unsigned short* Wcat3 = Wcat2 + 3 * 256 * 512;      // 3 x 128 x 256
    int* cnt     = (int*)(Wcat3 + 3 * 128 * 256);
    int* csr_pad = cnt + N_NODES;                       // N_NODES x 64
    size_t needed = (size_t)((char*)(csr_pad + (size_t)N_NODES * MAXDEG) - (char*)d_ws);
    if (ws_size < needed) return;

    // zero cnt (stream-ordered, graph-capturable)
    hipMemsetAsync(cnt, 0, N_NODES * sizeof(int), stream);

    // ONE setup launch: weight transposes + x convert + padded-CSR scatter tail
    {
        PrepJobs jb;
        const float* Ws_[9]  = {Wl1, Wr1, Ws1, Wl2, Wr2, Ws2, Wl3, Wr3, Ws3};
        unsigned short* Wt_[9] = {Wcat1, Wcat1 + 512 * 256, Wcat1 + 2 * 512 * 256,
                                  Wcat2, Wcat2 + 256 * 512, Wcat2 + 2 * 256 * 512,
                                  Wcat3, Wcat3 + 128 * 256, Wcat3 + 2 * 128 * 256};
        int K_[9] = {256, 256, 256, 512, 512, 512, 256, 256, 256};
        int D_[9] = {512, 512, 512, 256, 256, 256, 128, 128, 128};
        int o = 0;
        for (int i = 0; i < 9; ++i) {
            jb.W[i] = Ws_[i]; jb.Wt[i] = Wt_[i]; jb.K[i] = K_[i]; jb.D[i] = D_[i];
            jb.tbeg[i] = o; o += (K_[i] >> 5) * (D_[i] >> 5);
        }
        jb.tbeg[9] = o;                       // 864 tiles
        jb.x = x;
        jb.xh = xhf;
        jb.nconv4 = N_NODES * 256 / 4;
        jb.nconvb = (jb.nconv4 + 255) / 256;
        jb.src = src;
        jb.dst = dst;
        jb.cnt = cnt;
        jb.csr_pad = csr_pad;
        int nscatb = (N_EDGES + 255) / 256;
        hipLaunchKernelGGL(prep_kernel, dim3(o + jb.nconvb + nscatb), dim3(256), 0, stream, jb);
    }

    // layer 1: 256 -> 512, relu, f16 out
    run_layer(xhf, 256, 512, Wcat1, att1, bc1, bs1,
              xlh, xrh, seedh, (float*)nullptr, cnt, csr_pad,
              (float*)nullptr, h1h, 0, stream);
    // layer 2: 512 -> 256, relu, f16 out
    run_layer(h1h, 512, 256, Wcat2, att2, bc2, bs2,
              xlh, xrh, seedh, (float*)nullptr, cnt, csr_pad,
              (float*)nullptr, h2h, 0, stream);
    // layer 3: 256 -> 128, no relu, fp32 out; seed directly in d_out
    run_layer(h2h, 256, 128, Wcat3, att3, bc3, bs3,
              xlh, xrh, (unsigned short*)nullptr, (float*)d_out, cnt, csr_pad,
              (float*)d_out, (unsigned short*)nullptr, 1, stream);
}

// Round 16
// 304.124 us; speedup vs baseline: 1.0407x; 1.0407x over previous
//
#include <hip/hip_runtime.h>
#include <hip/hip_bf16.h>
#include <math.h>

#define N_NODES 20000
#define N_EDGES 320000
#define MAXDEG 64              // P(Poisson(16) >= 64) ~ 2e-18/node; clamped anyway

typedef _Float16 f16x8 __attribute__((ext_vector_type(8)));
typedef _Float16 h2 __attribute__((ext_vector_type(2)));
typedef float f32x4 __attribute__((ext_vector_type(4)));

__device__ __forceinline__ unsigned short f2h_bits(float f) {
    _Float16 h = (_Float16)f;            // RNE f32->f16
    return __builtin_bit_cast(unsigned short, h);
}

// async global->LDS DMA, 16B per lane; LDS dest = wave-uniform base + lane*16
typedef const unsigned int __attribute__((address_space(1)))* gas_ptr;
typedef unsigned int __attribute__((address_space(3)))* las_ptr;
__device__ __forceinline__ void gld16(const unsigned short* g, unsigned short* l) {
    __builtin_amdgcn_global_load_lds((gas_ptr)(const void*)g, (las_ptr)(void*)l, 16, 0, 0);
}

// ---------------------------------------------------------------------------
// setup (= R19/R22 exact, best measured 305.5): padded CSR, separate scatter.
// R24's BK=32 gemm regressed +11us -> reverted. R23's merged prep ~neutral
// -> reverted to the measured-best exact configuration.
// ---------------------------------------------------------------------------
__global__ void scatter_kernel(const int* __restrict__ src, const int* __restrict__ dst,
                               int* __restrict__ cnt, int* __restrict__ csr_pad, int E) {
    int i = blockIdx.x * blockDim.x + threadIdx.x;
    if (i < E) {
        int d = dst[i];
        int pos = atomicAdd(&cnt[d], 1);
        if (pos < MAXDEG) csr_pad[(d << 6) + pos] = src[i];
    }
}

// unified prep: 9 weight transposes (LDS-tiled, coalesced both sides) +
// x fp32->f16 conversion + cnt zeroing, in ONE launch (before scatter).
struct PrepJobs {
    const float* W[9];
    unsigned short* Wt[9];
    int K[9];
    int D[9];
    int tbeg[10];              // 32x32 tile prefix per transpose job
    const float* x;            // fp32 input
    unsigned short* xh;        // f16 output
    int nconv4;                // n/4 float4 groups
    int nconvb;                // conv blocks
    int* cnt;                  // zeroed here
};
__global__ __launch_bounds__(256) void prep_kernel(PrepJobs jb) {
    int bid = blockIdx.x;
    int ntile = jb.tbeg[9];
    if (bid < ntile) {
        __shared__ float ld[32][33];
        int job = 0;
        while (bid >= jb.tbeg[job + 1]) ++job;
        int tl = bid - jb.tbeg[job];
        int K = jb.K[job], D = jb.D[job];
        int TK = K >> 5;
        int td = tl / TK, tk = tl - td * TK;
        int k0 = tk << 5, d0 = td << 5;
        int t = threadIdx.x;
        int c = t & 31, r0 = (t >> 5) << 2;
        const float* Wp = jb.W[job];
#pragma unroll
        for (int jj = 0; jj < 4; ++jj)
            ld[r0 + jj][c] = Wp[(size_t)(k0 + r0 + jj) * D + d0 + c];   // coalesced
        __syncthreads();
        unsigned short* Wtp = jb.Wt[job];
#pragma unroll
        for (int jj = 0; jj < 4; ++jj) {
            int dr = r0 + jj;
            Wtp[(size_t)(d0 + dr) * K + k0 + c] = f2h_bits(ld[c][dr]);  // coalesced
        }
    } else if (bid < ntile + jb.nconvb) {
        int cidx = (bid - ntile) * 256 + (int)threadIdx.x;
        if (cidx < jb.nconv4) {
            int base = cidx * 4;
            float4 v = *(const float4*)(jb.x + base);
            uint2 pk;
            pk.x = (unsigned int)f2h_bits(v.x) | ((unsigned int)f2h_bits(v.y) << 16);
            pk.y = (unsigned int)f2h_bits(v.z) | ((unsigned int)f2h_bits(v.w) << 16);
            *(uint2*)(jb.xh + base) = pk;
        }
    } else {
        int i = (bid - ntile - jb.nconvb) * 256 + (int)threadIdx.x;
        if (i < N_NODES) jb.cnt[i] = 0;
    }
}

// ---------------------------------------------------------------------------
// fused 3-in-1 f16 MFMA GEMM (R22 exact: BK=64, T2 XOR-swizzle + counted-
// vmcnt double-buffer; bank conflicts 5.79M -> ~0; measured best).
// ---------------------------------------------------------------------------
template <int SEED_F32>
__global__ __launch_bounds__(256) void gemm3_kernel(
        const unsigned short* __restrict__ A,    // [M][K] f16
        const unsigned short* __restrict__ Bt,   // [3D][K] f16 (Wl^T|Wr^T|Ws^T)
        unsigned short* __restrict__ xlh,        // [M][D] f16
        unsigned short* __restrict__ xrh,        // [M][D] f16
        unsigned short* __restrict__ seedh,      // [M][D] f16 (SEED_F32==0)
        float* __restrict__ seedf,               // [M][D] fp32 (SEED_F32==1)
        const float* __restrict__ b1,
        const float* __restrict__ b2,
        int M, int K, int D) {
    __shared__ __align__(16) unsigned short Asl[2][128 * 64];
    __shared__ __align__(16) unsigned short Bsl[2][128 * 64];

    int NC = (3 * D) >> 7;               // column tiles
    int MT = (M + 127) >> 7;             // M tiles
    int g = blockIdx.x;
    int xcd = g & 7, slot = g >> 3;
    int m_local = slot / NC, c = slot - m_local * NC;
    int mt = m_local * 8 + xcd;
    if (mt >= MT) return;                // block-uniform -> safe before barriers

    int tid = threadIdx.x;
    int wave = tid >> 6, lane = tid & 63;
    int q = lane >> 4, t = lane & 15;
    int wm = (wave & 1) * 64, wn = (wave >> 1) * 64;
    int bm = mt << 7;
    int bn_all = c << 7;
    int seg = bn_all / D;                // D multiple of 128 -> block-uniform
    int bn = bn_all - seg * D;

    f32x4 acc[4][4];
#pragma unroll
    for (int i = 0; i < 4; ++i)
#pragma unroll
        for (int j = 0; j < 4; ++j) acc[i][j] = (f32x4){0.f, 0.f, 0.f, 0.f};

    int niter = K >> 6;

    // prologue: stage k-tile 0 into buffer 0 (8 vm ops/thread)
    {
#pragma unroll
        for (int rnd = 0; rnd < 4; ++rnd) {
            int ch = rnd * 256 + tid;
            int row = ch >> 3, part = ch & 7;
            int sw = part ^ (row & 7);                    // T2 pre-swizzle
            int gr = bm + row; if (gr >= M) gr = M - 1;
            gld16(A + (size_t)gr * K + sw * 8,
                  &Asl[0][(rnd * 256 + wave * 64) * 8]);
        }
#pragma unroll
        for (int rnd = 0; rnd < 4; ++rnd) {
            int ch = rnd * 256 + tid;
            int row = ch >> 3, part = ch & 7;
            int sw = part ^ (row & 7);
            gld16(Bt + (size_t)(bn_all + row) * K + sw * 8,
                  &Bsl[0][(rnd * 256 + wave * 64) * 8]);
        }
    }

    for (int i = 0; i < niter; ++i) {
        int cur = i & 1;
        if (i + 1 < niter) {
            int k0 = (i + 1) << 6;
            int nb = cur ^ 1;
#pragma unroll
            for (int rnd = 0; rnd < 4; ++rnd) {
                int ch = rnd * 256 + tid;
                int row = ch >> 3, part = ch & 7;
                int sw = part ^ (row & 7);
                int gr = bm + row; if (gr >= M) gr = M - 1;
                gld16(A + (size_t)gr * K + k0 + sw * 8,
                      &Asl[nb][(rnd * 256 + wave * 64) * 8]);
            }
#pragma unroll
            for (int rnd = 0; rnd < 4; ++rnd) {
                int ch = rnd * 256 + tid;
                int row = ch >> 3, part = ch & 7;
                int sw = part ^ (row & 7);
                gld16(Bt + (size_t)(bn_all + row) * K + k0 + sw * 8,
                      &Bsl[nb][(rnd * 256 + wave * 64) * 8]);
            }
            asm volatile("s_waitcnt vmcnt(8)" ::: "memory");   // drain iter i only
        } else {
            asm volatile("s_waitcnt vmcnt(0)" ::: "memory");   // final iter: drain all
        }
        __builtin_amdgcn_s_barrier();            // all waves' iter-i DMAs done
        __builtin_amdgcn_sched_barrier(0);       // pin: no LDS-read hoist above

#pragma unroll
        for (int kk = 0; kk < 2; ++kk) {
            f16x8 an[4], am[4];
#pragma unroll
            for (int jn = 0; jn < 4; ++jn) {
                int rb = wn + jn * 16 + t;
                an[jn] = *(const f16x8*)(&Bsl[cur][rb * 64 + ((((kk << 2) | q) ^ (rb & 7)) << 3)]);
            }
#pragma unroll
            for (int im = 0; im < 4; ++im) {
                int ra = wm + im * 16 + t;
                am[im] = *(const f16x8*)(&Asl[cur][ra * 64 + ((((kk << 2) | q) ^ (ra & 7)) << 3)]);
            }
#pragma unroll
            for (int jn = 0; jn < 4; ++jn)
#pragma unroll
                for (int im = 0; im < 4; ++im)
                    acc[jn][im] = __builtin_amdgcn_mfma_f32_16x16x32_f16(an[jn], am[im], acc[jn][im], 0, 0, 0);
        }
        __builtin_amdgcn_s_barrier();            // protect buf[cur] before reuse
        __builtin_amdgcn_sched_barrier(0);       // pin: no next-stage DMA hoist above
    }

#pragma unroll
    for (int jn = 0; jn < 4; ++jn) {
        int n0 = bn + wn + jn * 16 + q * 4;
        float bx = 0.f, by = 0.f, bz = 0.f, bw = 0.f;
        if (seg == 2) {
            float4 bb1 = *(const float4*)(b1 + n0);
            float4 bb2 = *(const float4*)(b2 + n0);
            bx = bb1.x + bb2.x; by = bb1.y + bb2.y;
            bz = bb1.z + bb2.z; bw = bb1.w + bb2.w;
        }
#pragma unroll
        for (int im = 0; im < 4; ++im) {
            int m = bm + wm + im * 16 + t;
            if (m < M) {
                float v0 = acc[jn][im][0] + bx;
                float v1 = acc[jn][im][1] + by;
                float v2 = acc[jn][im][2] + bz;
                float v3 = acc[jn][im][3] + bw;
                size_t idx = (size_t)m * D + n0;
                if (seg == 2 && SEED_F32) {
                    *(float4*)(seedf + idx) = make_float4(v0, v1, v2, v3);
                } else {
                    uint2 pk;
                    pk.x = (unsigned int)f2h_bits(v0) | ((unsigned int)f2h_bits(v1) << 16);
                    pk.y = (unsigned int)f2h_bits(v2) | ((unsigned int)f2h_bits(v3) << 16);
                    unsigned short* dstp = (seg == 0) ? xlh : (seg == 1) ? xrh : seedh;
                    *(uint2*)(dstp + idx) = pk;
                }
            }
        }
    }
}

// ---------------------------------------------------------------------------
// fused per-node agg (R19/R22 exact — best measured ~53.0us; closed after 6
// structural variants incl. R23's clean 512-thread occupancy probe (occ
// pinned at 40% regardless): random-gather miss-path floor ~3.4 TB/s eff.
// ---------------------------------------------------------------------------
template <int D, int SEED_H, int WRITE_H, int RELU>
__global__ __launch_bounds__(128) void fused_agg_kernel(
        const unsigned short* __restrict__ xl,
        const unsigned short* __restrict__ xr,
        const float* __restrict__ att,
        const int* __restrict__ cnt,
        const int* __restrict__ csr_pad,
        const unsigned short* __restrict__ seedh,
        const float* __restrict__ seedf,
        float* __restrict__ outf,
        unsigned short* __restrict__ outh) {
    constexpr int VPL = D / 64;
    constexpr int HP = VPL / 2;
    typedef _Float16 hvec __attribute__((ext_vector_type(VPL)));

    int wave = threadIdx.x >> 6, lane = threadIdx.x & 63;
    int n = blockIdx.x * 2 + wave;
    if (n >= N_NODES) return;
    int cn = cnt[n]; if (cn > MAXDEG) cn = MAXDEG;
    int beg = n << 6;
    int end = beg + cn;

    h2 xr_h[HP], att_h[HP];
    hvec xrv = *(const hvec*)(xr + (size_t)n * D + lane * VPL);
#pragma unroll
    for (int pp = 0; pp < HP; ++pp) {
        xr_h[pp] = (h2){xrv[2 * pp], xrv[2 * pp + 1]};
        att_h[pp] = (h2){(_Float16)att[lane * VPL + 2 * pp],
                         (_Float16)att[lane * VPL + 2 * pp + 1]};
    }

    float acc[VPL];
#pragma unroll
    for (int v = 0; v < VPL; ++v) acc[v] = 0.f;
    float m = -INFINITY, s = 0.f;

    const _Float16 c02 = (_Float16)0.2f;
    int lb0 = lane & 1;
    int lb1 = lane & 2;

    int nfull = cn >> 2;
    int j = beg;
    int i0 = 0, i1 = 0, i2 = 0, i3 = 0;
    if (nfull > 0) {
        i0 = csr_pad[beg]; i1 = csr_pad[beg + 1];
        i2 = csr_pad[beg + 2]; i3 = csr_pad[beg + 3];
    }
    for (int b = 0; b < nfull; ++b) {
        int s0 = i0, s1 = i1, s2 = i2, s3 = i3;
        int jn4 = j + 4;
        if (b + 1 < nfull) {            // prefetch next batch's indices
            i0 = csr_pad[jn4]; i1 = csr_pad[jn4 + 1];
            i2 = csr_pad[jn4 + 2]; i3 = csr_pad[jn4 + 3];
        }
        hvec x0 = *(const hvec*)(xl + (size_t)s0 * D + lane * VPL);
        hvec x1 = *(const hvec*)(xl + (size_t)s1 * D + lane * VPL);
        hvec x2 = *(const hvec*)(xl + (size_t)s2 * D + lane * VPL);
        hvec x3 = *(const hvec*)(xl + (size_t)s3 * D + lane * VPL);
        float p0 = 0.f, p1 = 0.f, p2 = 0.f, p3 = 0.f;
#pragma unroll
        for (int pp = 0; pp < HP; ++pp) {
            h2 a0 = (h2){x0[2 * pp], x0[2 * pp + 1]};
            h2 a1 = (h2){x1[2 * pp], x1[2 * pp + 1]};
            h2 a2 = (h2){x2[2 * pp], x2[2 * pp + 1]};
            h2 a3 = (h2){x3[2 * pp], x3[2 * pp + 1]};
            h2 z0 = a0 + xr_h[pp];
            h2 z1 = a1 + xr_h[pp];
            h2 z2 = a2 + xr_h[pp];
            h2 z3 = a3 + xr_h[pp];
            h2 l0 = __builtin_elementwise_max(z0, z0 * c02);   // leaky_relu
            h2 l1 = __builtin_elementwise_max(z1, z1 * c02);
            h2 l2 = __builtin_elementwise_max(z2, z2 * c02);
            h2 l3 = __builtin_elementwise_max(z3, z3 * c02);
#if __has_builtin(__builtin_amdgcn_fdot2)
            p0 = __builtin_amdgcn_fdot2(l0, att_h[pp], p0, false);
            p1 = __builtin_amdgcn_fdot2(l1, att_h[pp], p1, false);
            p2 = __builtin_amdgcn_fdot2(l2, att_h[pp], p2, false);
            p3 = __builtin_amdgcn_fdot2(l3, att_h[pp], p3, false);
#else
            p0 += (float)l0.x * (float)att_h[pp].x + (float)l0.y * (float)att_h[pp].y;
            p1 += (float)l1.x * (float)att_h[pp].x + (float)l1.y * (float)att_h[pp].y;
            p2 += (float)l2.x * (float)att_h[pp].x + (float)l2.y * (float)att_h[pp].y;
            p3 += (float)l3.x * (float)att_h[pp].x + (float)l3.y * (float)att_h[pp].y;
#endif
        }
        // butterfly tree: stride 1 (4->2 regs), stride 2 (2->1), strides 4..32
        float k0 = lb0 ? p1 : p0, sn0 = lb0 ? p0 : p1;
        float k1 = lb0 ? p3 : p2, sn1 = lb0 ? p2 : p3;
        k0 += __shfl_xor(sn0, 1, 64);
        k1 += __shfl_xor(sn1, 1, 64);
        float k = lb1 ? k1 : k0, sn = lb1 ? k0 : k1;
        k += __shfl_xor(sn, 2, 64);
        k += __shfl_xor(k, 4, 64);
        k += __shfl_xor(k, 8, 64);
        k += __shfl_xor(k, 16, 64);
        k += __shfl_xor(k, 32, 64);
        // lane l holds full score of edge (l&3); broadcast all four
        float q0 = __shfl(k, 0, 64);
        float q1 = __shfl(k, 1, 64);
        float q2 = __shfl(k, 2, 64);
        float q3 = __shfl(k, 3, 64);

        float mn = fmaxf(m, fmaxf(fmaxf(q0, q1), fmaxf(q2, q3)));
        float sc = __expf(m - mn);           // first iter: exp(-inf)=0
        float e0 = __expf(q0 - mn);
        float e1 = __expf(q1 - mn);
        float e2 = __expf(q2 - mn);
        float e3 = __expf(q3 - mn);
        s = s * sc + e0 + e1 + e2 + e3;
#pragma unroll
        for (int v = 0; v < VPL; ++v)
            acc[v] = acc[v] * sc + e0 * (float)x0[v] + e1 * (float)x1[v]
                                 + e2 * (float)x2[v] + e3 * (float)x3[v];
        m = mn;
        j = jn4;
    }
    for (; j < end; ++j) {   // tail (0-3 edges)
        int s0 = csr_pad[j];
        hvec x0 = *(const hvec*)(xl + (size_t)s0 * D + lane * VPL);
        float p0 = 0.f;
#pragma unroll
        for (int pp = 0; pp < HP; ++pp) {
            h2 a0 = (h2){x0[2 * pp], x0[2 * pp + 1]};
            h2 z0 = a0 + xr_h[pp];
            h2 l0 = __builtin_elementwise_max(z0, z0 * c02);
#if __has_builtin(__builtin_amdgcn_fdot2)
            p0 = __builtin_amdgcn_fdot2(l0, att_h[pp], p0, false);
#else
            p0 += (float)l0.x * (float)att_h[pp].x + (float)l0.y * (float)att_h[pp].y;
#endif
        }
#pragma unroll
        for (int o = 32; o > 0; o >>= 1) p0 += __shfl_xor(p0, o, 64);
        float mn = fmaxf(m, p0);
        float sc = __expf(m - mn);
        float e0 = __expf(p0 - mn);
        s = s * sc + e0;
#pragma unroll
        for (int v = 0; v < VPL; ++v) acc[v] = acc[v] * sc + e0 * (float)x0[v];
        m = mn;
    }

    float sinv = 1.0f / (s + 1e-16f);
    size_t base = (size_t)n * D + lane * VPL;
    float sd[VPL];
    if (SEED_H) {
        hvec sv = *(const hvec*)(seedh + base);
#pragma unroll
        for (int v = 0; v < VPL; ++v) sd[v] = (float)sv[v];
    } else {
#pragma unroll
        for (int v = 0; v < VPL; ++v) sd[v] = seedf[base + v];
    }
#pragma unroll
    for (int v = 0; v < VPL; ++v) {
        float val = sd[v] + acc[v] * sinv;
        if (RELU) val = fmaxf(val, 0.f);
        if (WRITE_H) outh[base + v] = f2h_bits(val);
        else         outf[base + v] = val;
    }
}

// ---------------------------------------------------------------------------
// host-side layer driver
// ---------------------------------------------------------------------------
static void run_layer(const unsigned short* hact, int K, int D,
                      const unsigned short* Wcat,
                      const float* att, const float* bc, const float* bs,
                      unsigned short* xlh, unsigned short* xrh,
                      unsigned short* seedh, float* seedf,
                      const int* cnt, const int* csr_pad,
                      float* outf, unsigned short* outh, int final_layer,
                      hipStream_t stream) {
    int NC = 3 * D / 128;
    int MT = (N_NODES + 127) / 128;
    int nblk = 8 * ((MT + 7) / 8) * NC;   // XCD-swizzled 1D grid
    if (final_layer)
        hipLaunchKernelGGL((gemm3_kernel<1>), dim3(nblk), dim3(256), 0, stream, hact, Wcat,
                           xlh, xrh, (unsigned short*)nullptr, seedf, bs, bc, N_NODES, K, D);
    else
        hipLaunchKernelGGL((gemm3_kernel<0>), dim3(nblk), dim3(256), 0, stream, hact, Wcat,
                           xlh, xrh, seedh, (float*)nullptr, bs, bc, N_NODES, K, D);

    dim3 agrid((N_NODES + 1) / 2);
    if (D == 512) {
        hipLaunchKernelGGL((fused_agg_kernel<512, 1, 1, 1>), agrid, dim3(128), 0, stream,
                           xlh, xrh, att, cnt, csr_pad, seedh, (const float*)nullptr,
                           (float*)nullptr, outh);
    } else if (D == 256) {
        hipLaunchKernelGGL((fused_agg_kernel<256, 1, 1, 1>), agrid, dim3(128), 0, stream,
                           xlh, xrh, att, cnt, csr_pad, seedh, (const float*)nullptr,
                           (float*)nullptr, outh);
    } else {
        hipLaunchKernelGGL((fused_agg_kernel<128, 0, 0, 0>), agrid, dim3(128), 0, stream,
                           xlh, xrh, att, cnt, csr_pad, (const unsigned short*)nullptr, seedf,
                           outf, (unsigned short*)nullptr);
    }
}

extern "C" void kernel_launch(void* const* d_in, const int* in_sizes, int n_in,
                              void* d_out, int out_size, void* d_ws, size_t ws_size,
                              hipStream_t stream) {
    const float* x = (const float*)d_in[0];
    const int* ei = (const int*)d_in[1];
    const int* src = ei;
    const int* dst = ei + N_EDGES;

    const float* Wl1 = (const float*)d_in[2];
    const float* Wr1 = (const float*)d_in[3];
    const float* att1 = (const float*)d_in[4];
    const float* bc1 = (const float*)d_in[5];
    const float* Ws1 = (const float*)d_in[6];
    const float* bs1 = (const float*)d_in[7];
    const float* Wl2 = (const float*)d_in[8];
    const float* Wr2 = (const float*)d_in[9];
    const float* att2 = (const float*)d_in[10];
    const float* bc2 = (const float*)d_in[11];
    const float* Ws2 = (const float*)d_in[12];
    const float* bs2 = (const float*)d_in[13];
    const float* Wl3 = (const float*)d_in[14];
    const float* Wr3 = (const float*)d_in[15];
    const float* att3 = (const float*)d_in[16];
    const float* bc3 = (const float*)d_in[17];
    const float* Ws3 = (const float*)d_in[18];
    const float* bs3 = (const float*)d_in[19];

    // workspace carve
    const size_t NF = (size_t)N_NODES * 512;
    const size_t NH = (size_t)N_NODES * 256;
    unsigned short* xlh   = (unsigned short*)d_ws;      // N x 512 f16 (reused per layer)
    unsigned short* xrh   = xlh + NF;
    unsigned short* seedh = xrh + NF;                   // N x 512 f16 (layers 1-2)
    unsigned short* xhf   = seedh + NF;                 // x as f16: N x 256
    unsigned short* h1h   = xhf + NH;                   // layer1 out: N x 512
    unsigned short* h2h   = h1h + NF;                   // layer2 out: N x 256
    unsigned short* Wcat1 = h2h + NH;                   // 3 x 512 x 256
    unsigned short* Wcat2 = Wcat1 + 3 * 512 * 256;      // 3 x 256 x 512
    unsigned short* Wcat3 = Wcat2 + 3 * 256 * 512;      // 3 x 128 x 256
    int* cnt     = (int*)(Wcat3 + 3 * 128 * 256);
    int* csr_pad = cnt + N_NODES;                       // N_NODES x 64
    size_t needed = (size_t)((char*)(csr_pad + (size_t)N_NODES * MAXDEG) - (char*)d_ws);
    if (ws_size < needed) return;

    // setup launch 1: weight transposes + x convert + zero cnt
    {
        PrepJobs jb;
        const float* Ws_[9]  = {Wl1, Wr1, Ws1, Wl2, Wr2, Ws2, Wl3, Wr3, Ws3};
        unsigned short* Wt_[9] = {Wcat1, Wcat1 + 512 * 256, Wcat1 + 2 * 512 * 256,
                                  Wcat2, Wcat2 + 256 * 512, Wcat2 + 2 * 256 * 512,
                                  Wcat3, Wcat3 + 128 * 256, Wcat3 + 2 * 128 * 256};
        int K_[9] = {256, 256, 256, 512, 512, 512, 256, 256, 256};
        int D_[9] = {512, 512, 512, 256, 256, 256, 128, 128, 128};
        int o = 0;
        for (int i = 0; i < 9; ++i) {
            jb.W[i] = Ws_[i]; jb.Wt[i] = Wt_[i]; jb.K[i] = K_[i]; jb.D[i] = D_[i];
            jb.tbeg[i] = o; o += (K_[i] >> 5) * (D_[i] >> 5);
        }
        jb.tbeg[9] = o;                       // 864 tiles
        jb.x = x;
        jb.xh = xhf;
        jb.nconv4 = N_NODES * 256 / 4;
        jb.nconvb = (jb.nconv4 + 255) / 256;
        jb.cnt = cnt;
        int nzerob = (N_NODES + 255) / 256;
        hipLaunchKernelGGL(prep_kernel, dim3(o + jb.nconvb + nzerob), dim3(256), 0, stream, jb);
    }
    // setup launch 2: padded-CSR scatter
    hipLaunchKernelGGL(scatter_kernel, dim3((N_EDGES + 255) / 256), dim3(256), 0, stream,
                       src, dst, cnt, csr_pad, N_EDGES);

    // layer 1: 256 -> 512, relu, f16 out
    run_layer(xhf, 256, 512, Wcat1, att1, bc1, bs1,
              xlh, xrh, seedh, (float*)nullptr, cnt, csr_pad,
              (float*)nullptr, h1h, 0, stream);
    // layer 2: 512 -> 256, relu, f16 out
    run_layer(h1h, 512, 256, Wcat2, att2, bc2, bs2,
              xlh, xrh, seedh, (float*)nullptr, cnt, csr_pad,
              (float*)nullptr, h2h, 0, stream);
    // layer 3: 256 -> 128, no relu, fp32 out; seed directly in d_out
    run_layer(h2h, 256, 128, Wcat3, att3, bc3, bs3,
              xlh, xrh, (unsigned short*)nullptr, (float*)d_out, cnt, csr_pad,
              (float*)d_out, (unsigned short*)nullptr, 1, stream);
}